// Round 1
// 3351.592 us; speedup vs baseline: 1.5439x; 1.5439x over previous
//
#include <hip/hip_runtime.h>
#include <cstdint>

#define BATCH 64
#define NODES 207
#define HID   64
#define NH    (NODES*HID)      // 13248
#define TOT   (BATCH*NH)       // 847872
#define NSTEPS 100
#define MT 28                  // m-rows per block tile
#define NT 8                   // ceil(NODES/MT) = 8 -> grid 64x8 = 512 blocks = 2/CU
#define RPW 7                  // rows per wave (MT / 4 waves)

// ---------------- threefry2x32 (JAX semantics) ----------------
__device__ __forceinline__ uint32_t rotl32(uint32_t v, int n) {
    return (v << n) | (v >> (32 - n));
}

__device__ __forceinline__ void threefry2x32(uint32_t k0, uint32_t k1,
                                             uint32_t& x0, uint32_t& x1) {
    uint32_t ks0 = k0, ks1 = k1, ks2 = k0 ^ k1 ^ 0x1BD11BDAu;
    x0 += ks0; x1 += ks1;
#define TF_ROUND(r) { x0 += x1; x1 = rotl32(x1, (r)); x1 ^= x0; }
    TF_ROUND(13) TF_ROUND(15) TF_ROUND(26) TF_ROUND(6)
    x0 += ks1; x1 += ks2 + 1u;
    TF_ROUND(17) TF_ROUND(29) TF_ROUND(16) TF_ROUND(24)
    x0 += ks2; x1 += ks0 + 2u;
    TF_ROUND(13) TF_ROUND(15) TF_ROUND(26) TF_ROUND(6)
    x0 += ks0; x1 += ks1 + 3u;
    TF_ROUND(17) TF_ROUND(29) TF_ROUND(16) TF_ROUND(24)
    x0 += ks1; x1 += ks2 + 4u;
    TF_ROUND(13) TF_ROUND(15) TF_ROUND(26) TF_ROUND(6)
    x0 += ks2; x1 += ks0 + 5u;
#undef TF_ROUND
}

// ---------------- erfinv (XLA f32 path, Giles) ----------------
__device__ __forceinline__ float erfinv32(float x) {
    float w = -log1pf(-x * x);
    float p;
    if (w < 5.0f) {
        w = w - 2.5f;
        p =             2.81022636e-08f;
        p = fmaf(p, w,  3.43273939e-07f);
        p = fmaf(p, w, -3.5233877e-06f);
        p = fmaf(p, w, -4.39150654e-06f);
        p = fmaf(p, w,  0.00021858087f);
        p = fmaf(p, w, -0.00125372503f);
        p = fmaf(p, w, -0.00417768164f);
        p = fmaf(p, w,  0.246640727f);
        p = fmaf(p, w,  1.50140941f);
    } else {
        w = sqrtf(w) - 3.0f;
        p =            -0.000200214257f;
        p = fmaf(p, w,  0.000100950558f);
        p = fmaf(p, w,  0.00134934322f);
        p = fmaf(p, w, -0.00367342844f);
        p = fmaf(p, w,  0.00573950773f);
        p = fmaf(p, w, -0.0076224613f);
        p = fmaf(p, w,  0.00943887047f);
        p = fmaf(p, w,  1.00167406f);
        p = fmaf(p, w,  2.83297682f);
    }
    return p * x;
}

// bits -> N(0,1) matching jax.random.normal f32 path
__device__ __forceinline__ float bits_to_normal(uint32_t bits) {
    uint32_t fb = (bits >> 9) | 0x3f800000u;
    float f = __uint_as_float(fb) - 1.0f;   // [0,1)
    const float lo = -0.99999994f;          // nextafter(-1,0)
    float u = f * 2.0f + lo;                // (maxval-minval) rounds to 2.0f
    u = fmaxf(lo, u);
    return 1.41421356237f * erfinv32(u);    // sqrt(2) f32
}

// ---------------- kernels ----------------

// y <- x copy, and derive the 100 step keys:
// partitionable split: key_s = threefry2x32((0,42), hi=0, lo=s)
__global__ void k_init(const float* __restrict__ x, float* __restrict__ y,
                       uint32_t* __restrict__ keys) {
    int tid = blockIdx.x * blockDim.x + threadIdx.x;
    int n4 = TOT / 4;
    int stride = gridDim.x * blockDim.x;
    for (int i = tid; i < n4; i += stride) {
        ((float4*)y)[i] = ((const float4*)x)[i];
    }
    if (tid < NSTEPS) {
        uint32_t x0 = 0u, x1 = (uint32_t)tid;
        threefry2x32(0u, 42u, x0, x1);
        keys[2*tid]   = x0;
        keys[2*tid+1] = x1;
    }
}

// Fused Euler-Maruyama step: one block = (batch b, 28-row m-tile).
// AY = A@Y (register-blocked 7 rows/wave, A via wave-uniform scalar loads),
// then T/D 64x64 GEMMs from wave-private LDS scratch, noise, y-update.
// Ping-pong y buffers remove the global ay round trip.
__global__ __launch_bounds__(256) void k_fused(const float* __restrict__ A,
                                               const float* __restrict__ yin,
                                               float* __restrict__ yout,
                                               const float* __restrict__ Wt,
                                               const float* __restrict__ bt,
                                               const float* __restrict__ Wd,
                                               const float* __restrict__ bd,
                                               const uint32_t* __restrict__ keys,
                                               int s) {
    __shared__ float Ylds[NH];            // 52.99 KB
    __shared__ float AYlds[MT * HID];     // 7 KB  -> 59.99 KB total, 2 blocks/CU
    int b  = blockIdx.x;                  // 0..63
    int m0 = blockIdx.y * MT;             // 0,28,...,196
    const float* yb = yin + (size_t)b * NH;
    for (int i = threadIdx.x; i < NH/4; i += 256) {
        ((float4*)Ylds)[i] = ((const float4*)yb)[i];
    }
    __syncthreads();

    int h = threadIdx.x & 63;
    // wave id, forced wave-uniform so row indices (and A addresses) scalarize
    int w = __builtin_amdgcn_readfirstlane((int)(threadIdx.x >> 6));

    // ---- AY phase: 7 rows per wave (stride 4), 7 fma per 1 ds_read ----
    const float* Arow[RPW];
#pragma unroll
    for (int i = 0; i < RPW; ++i) {
        int m = m0 + i*4 + w;
        int mc = (m < NODES) ? m : (NODES - 1);   // clamp; garbage rows never stored
        Arow[i] = A + (size_t)mc * NODES;
    }
    float acc[RPW];
#pragma unroll
    for (int i = 0; i < RPW; ++i) acc[i] = 0.0f;
    for (int n = 0; n < NODES; ++n) {
        float yv = Ylds[n*HID + h];
#pragma unroll
        for (int i = 0; i < RPW; ++i)
            acc[i] = fmaf(Arow[i][n], yv, acc[i]);   // same n-order as before
    }
    // park AY rows in wave-private LDS scratch (no barrier needed: writer==reader wave)
#pragma unroll
    for (int i = 0; i < RPW; ++i) {
        int ri = i*4 + w;                 // 0..27, disjoint across waves
        AYlds[ri*HID + h] = acc[i];
    }

    // ---- T/D phase: per k, broadcast ds_read amortized over T and D ----
    float accT[RPW], accD[RPW];
#pragma unroll
    for (int i = 0; i < RPW; ++i) { accT[i] = 0.0f; accD[i] = 0.0f; }
    for (int k = 0; k < HID; ++k) {
        float wt = Wt[k*HID + h];         // coalesced, L1/L2-resident (16 KB each)
        float wd = Wd[k*HID + h];
#pragma unroll
        for (int i = 0; i < RPW; ++i) {
            float a = AYlds[(i*4 + w)*HID + k];   // same-address broadcast read
            accT[i] = fmaf(a, wt, accT[i]);       // same k-order as before
            accD[i] = fmaf(a, wd, accD[i]);
        }
    }

    // ---- noise + update ----
    uint32_t kk0 = keys[2*s], kk1 = keys[2*s+1];
    float btv = bt[h], bdv = bd[h];
#pragma unroll
    for (int i = 0; i < RPW; ++i) {
        int m = m0 + i*4 + w;
        if (m < NODES) {                  // wave-uniform branch
            float F = 0.1f * tanhf(accT[i] + btv);
            float G = 0.1f * tanhf(accD[i] + bdv);
            uint32_t j = (uint32_t)(((size_t)b*NODES + m)*HID + h);
            uint32_t x0 = 0u, x1 = j;
            threefry2x32(kk0, kk1, x0, x1);
            float nrm = bits_to_normal(x0 ^ x1);
            float dW  = 0.1f * nrm;       // sqrt(0.01f) == 0.1f in f32
            float yold = Ylds[m*HID + h];
            size_t idx = (size_t)b*NH + (size_t)m*HID + h;
            yout[idx] = (yold + F * 0.01f) + G * dW;
        }
    }
}

// out[row, col] = tanh(sum_k y[row,k]*Wo[k,col] + bo[col])
// LDS-free: y values are wave-uniform -> scalar loads feed fma's SGPR operand.
#define OR 16
__global__ __launch_bounds__(256) void k_out(const float* __restrict__ y,
                                             const float* __restrict__ Wo,
                                             const float* __restrict__ bo,
                                             float* __restrict__ out) {
    int r0  = blockIdx.x * OR;            // 828 tiles
    int col = blockIdx.y * 256 + threadIdx.x;
    const float* yb = y + (size_t)r0 * HID;
    float acc[OR];
#pragma unroll
    for (int r = 0; r < OR; ++r) acc[r] = 0.0f;
#pragma unroll 4
    for (int k = 0; k < HID; ++k) {
        float wv = Wo[(size_t)k*4096 + col];
#pragma unroll
        for (int r = 0; r < OR; ++r)
            acc[r] = fmaf(yb[r*HID + k], wv, acc[r]);   // yb[..] uniform -> s_load
    }
    float bb = bo[col];
#pragma unroll
    for (int r = 0; r < OR; ++r)
        out[(size_t)(r0 + r)*4096 + col] = tanhf(acc[r] + bb);
}

extern "C" void kernel_launch(void* const* d_in, const int* in_sizes, int n_in,
                              void* d_out, int out_size, void* d_ws, size_t ws_size,
                              hipStream_t stream) {
    const float* x  = (const float*)d_in[0];
    const float* A  = (const float*)d_in[1];
    const float* Wt = (const float*)d_in[2];
    const float* bt = (const float*)d_in[3];
    const float* Wd = (const float*)d_in[4];
    const float* bd = (const float*)d_in[5];
    const float* Wo = (const float*)d_in[6];
    const float* bo = (const float*)d_in[7];
    float* out = (float*)d_out;

    float* y0 = (float*)d_ws;                 // 3.39 MB
    float* y1 = y0 + TOT;                     // 3.39 MB (ping-pong)
    uint32_t* keys = (uint32_t*)(y1 + TOT);   // 800 B

    k_init<<<512, 256, 0, stream>>>(x, y0, keys);
    float* cur = y0;
    float* nxt = y1;
    for (int s = 0; s < NSTEPS; ++s) {
        k_fused<<<dim3(BATCH, NT), 256, 0, stream>>>(A, cur, nxt, Wt, bt, Wd, bd, keys, s);
        float* t = cur; cur = nxt; nxt = t;
    }
    // NSTEPS even -> final state is back in y0, but use `cur` regardless
    k_out<<<dim3(NH/OR, 4096/256), 256, 0, stream>>>(cur, Wo, bo, out);
}